// Round 5
// baseline (667.611 us; speedup 1.0000x reference)
//
#include <hip/hip_runtime.h>

#define EPS 1e-7f
#define NCH 29
#define SAMP_PER_WAVE 64
#define SAMP_PER_BLK 256   // 4 waves * 64 samples

// LDS weight image (floats). One MLP set = 99*29 = 2871 floats.
// [W0 29*35][b0 29*5][W1 29*20][b1 29*4][W2 29*16][b2 29*4][W3 29*12][b3 29*3]
#define OFF_W0 0
#define OFF_B0 (29*35)
#define OFF_W1 (OFF_B0 + 29*5)
#define OFF_B1 (OFF_W1 + 29*20)
#define OFF_W2 (OFF_B1 + 29*4)
#define OFF_B2 (OFF_W2 + 29*16)
#define OFF_W3 (OFF_B2 + 29*4)
#define OFF_B3 (OFF_W3 + 29*12)
#define SETSZ  (OFF_B3 + 29*3)   // 2871

typedef float f32x2 __attribute__((ext_vector_type(2)));

__device__ __forceinline__ f32x2 splat2(float v) { f32x2 r; r.x = v; r.y = v; return r; }
__device__ __forceinline__ f32x2 fma2(f32x2 a, f32x2 b, f32x2 c) {
    return __builtin_elementwise_fma(a, b, c);
}
__device__ __forceinline__ f32x2 max2(f32x2 a, f32x2 b) {
    return __builtin_elementwise_max(a, b);
}
__device__ __forceinline__ f32x2 expc2(f32x2 a) {
    f32x2 r; r.x = __expf(a.x); r.y = __expf(a.y); return r;
}
__device__ __forceinline__ f32x2 rcp2(f32x2 a) {
    f32x2 r; r.x = __builtin_amdgcn_rcpf(a.x); r.y = __builtin_amdgcn_rcpf(a.y); return r;
}

__device__ __forceinline__ void stage(float* dst, const float* __restrict__ src,
                                      int n, int tid) {
    for (int i = tid; i < n; i += 256) dst[i] = src[i];
}

__global__ __launch_bounds__(256, 3) void lps_kernel(
    const float* __restrict__ tau, const float* __restrict__ mu, const float* __restrict__ mu_bar,
    const float* __restrict__ lw, const float* __restrict__ h2o, const float* __restrict__ o3,
    const float* __restrict__ co2, const float* __restrict__ uu, const float* __restrict__ n2o,
    const float* __restrict__ ch4,
    const float* __restrict__ Wd0, const float* __restrict__ bd0,
    const float* __restrict__ Wf0, const float* __restrict__ bf0,
    const float* __restrict__ Wd1, const float* __restrict__ bd1,
    const float* __restrict__ Wf1, const float* __restrict__ bf1,
    const float* __restrict__ Wd2, const float* __restrict__ bd2,
    const float* __restrict__ Wf2, const float* __restrict__ bf2,
    const float* __restrict__ Wd3, const float* __restrict__ bd3,
    const float* __restrict__ Wf3, const float* __restrict__ bf3,
    float* __restrict__ out, int N)
{
    __shared__ float wlds[2 * SETSZ];   // 22968 B

    const int tid = threadIdx.x;

    // ---- one-time: stage all weights into LDS (coalesced) ----
    stage(wlds + OFF_W0,         Wd0, 29*35, tid);
    stage(wlds + OFF_B0,         bd0, 29*5,  tid);
    stage(wlds + OFF_W1,         Wd1, 29*20, tid);
    stage(wlds + OFF_B1,         bd1, 29*4,  tid);
    stage(wlds + OFF_W2,         Wd2, 29*16, tid);
    stage(wlds + OFF_B2,         bd2, 29*4,  tid);
    stage(wlds + OFF_W3,         Wd3, 29*12, tid);
    stage(wlds + OFF_B3,         bd3, 29*3,  tid);
    stage(wlds + SETSZ + OFF_W0, Wf0, 29*35, tid);
    stage(wlds + SETSZ + OFF_B0, bf0, 29*5,  tid);
    stage(wlds + SETSZ + OFF_W1, Wf1, 29*20, tid);
    stage(wlds + SETSZ + OFF_B1, bf1, 29*4,  tid);
    stage(wlds + SETSZ + OFF_W2, Wf2, 29*16, tid);
    stage(wlds + SETSZ + OFF_B2, bf2, 29*4,  tid);
    stage(wlds + SETSZ + OFF_W3, Wf3, 29*12, tid);
    stage(wlds + SETSZ + OFF_B3, bf3, 29*3,  tid);
    __syncthreads();   // only barrier in the kernel (prologue)

    const int lane = tid & 63;
    const int wid  = __builtin_amdgcn_readfirstlane(tid >> 6);
    const int h    = lane & 1;          // 0: first half (direct), 1: second half (diffuse)
    int c = lane >> 1; if (c > NCH - 1) c = NCH - 1;
    const bool active = (lane < 2 * NCH);

    // ---- per-lane weights -> registers (statically indexed everywhere) ----
    const float* wb = wlds + (h ? SETSZ : 0);
    float w0[35], w1[20], w2[16], w3[12], b0r[5], b1r[4], b2r[4], b3r[3];
#pragma unroll
    for (int j = 0; j < 35; ++j) w0[j]  = wb[OFF_W0 + c*35 + j];
#pragma unroll
    for (int j = 0; j < 5;  ++j) b0r[j] = wb[OFF_B0 + c*5  + j];
#pragma unroll
    for (int j = 0; j < 20; ++j) w1[j]  = wb[OFF_W1 + c*20 + j];
#pragma unroll
    for (int j = 0; j < 4;  ++j) b1r[j] = wb[OFF_B1 + c*4  + j];
#pragma unroll
    for (int j = 0; j < 16; ++j) w2[j]  = wb[OFF_W2 + c*16 + j];
#pragma unroll
    for (int j = 0; j < 4;  ++j) b2r[j] = wb[OFF_B2 + c*4  + j];
#pragma unroll
    for (int j = 0; j < 12; ++j) w3[j]  = wb[OFF_W3 + c*12 + j];
#pragma unroll
    for (int j = 0; j < 3;  ++j) b3r[j] = wb[OFF_B3 + c*3  + j];

    const long long wbase = (long long)blockIdx.x * SAMP_PER_BLK
                          + (long long)wid * SAMP_PER_WAVE;
    float4* out4 = (float4*)out;

    for (int it = 0; it < SAMP_PER_WAVE / 2; ++it) {
        const long long s = wbase + it * 2;
        const int i0 = (s     < N) ? (int)s       : (N - 1);
        const int i1 = (s + 1 < N) ? (int)(s + 1) : (N - 1);

        // per-sample scalars (wave-uniform addresses)
        f32x2 mu2, mub2;
        mu2.x  = mu[i0];     mu2.y  = mu[i1];
        mub2.x = mu_bar[i0]; mub2.y = mu_bar[i1];
        const f32x2 r_mu  = rcp2(mu2  + splat2(EPS));
        const f32x2 r_mub = rcp2(mub2 + splat2(EPS));
        const f32x2 rsel  = h ? r_mub : r_mu;   // this lane's MLP input scale

        f32x2 x2[7];
        { f32x2 t; t.x = lw[i0];  t.y = lw[i1];  x2[0] = t * rsel; }
        { f32x2 t; t.x = h2o[i0]; t.y = h2o[i1]; x2[1] = t * rsel; }
        { f32x2 t; t.x = o3[i0];  t.y = o3[i1];  x2[2] = t * rsel; }
        { f32x2 t; t.x = co2[i0]; t.y = co2[i1]; x2[3] = t * rsel; }
        { f32x2 t; t.x = uu[i0];  t.y = uu[i1];  x2[4] = t * rsel; }
        { f32x2 t; t.x = n2o[i0]; t.y = n2o[i1]; x2[5] = t * rsel; }
        { f32x2 t; t.x = ch4[i0]; t.y = ch4[i1]; x2[6] = t * rsel; }

        f32x2 tau2;
        tau2.x = tau[(size_t)i0 * NCH + c];
        tau2.y = tau[(size_t)i1 * NCH + c];
        const f32x2 td = expc2(-(tau2 * r_mu));
        const f32x2 tf = expc2(-(tau2 * r_mub));

        // ---- this lane's MLP (weights in VGPRs, fully unrolled) ----
        const f32x2 zero = splat2(0.0f);
        f32x2 h0[5];
#pragma unroll
        for (int k = 0; k < 5; ++k) {
            f32x2 a = splat2(b0r[k]);
#pragma unroll
            for (int f = 0; f < 7; ++f) a = fma2(x2[f], splat2(w0[f*5 + k]), a);
            h0[k] = max2(a, zero);
        }
        f32x2 h1[4];
#pragma unroll
        for (int k = 0; k < 4; ++k) {
            f32x2 a = splat2(b1r[k]);
#pragma unroll
            for (int f = 0; f < 5; ++f) a = fma2(h0[f], splat2(w1[f*4 + k]), a);
            h1[k] = max2(a, zero);
        }
        f32x2 h2[4];
#pragma unroll
        for (int k = 0; k < 4; ++k) {
            f32x2 a = splat2(b2r[k]);
#pragma unroll
            for (int f = 0; f < 4; ++f) a = fma2(h1[f], splat2(w2[f*4 + k]), a);
            h2[k] = max2(a, zero);
        }
        f32x2 l0 = splat2(b3r[0]), l1 = splat2(b3r[1]), l2 = splat2(b3r[2]);
#pragma unroll
        for (int f = 0; f < 4; ++f) {
            l0 = fma2(h2[f], splat2(w3[f*3 + 0]), l0);
            l1 = fma2(h2[f], splat2(w3[f*3 + 1]), l1);
            l2 = fma2(h2[f], splat2(w3[f*3 + 2]), l2);
        }
        const f32x2 m  = max2(l0, max2(l1, l2));
        const f32x2 e0 = expc2(l0 - m);
        const f32x2 e1 = expc2(l1 - m);
        const f32x2 e2 = expc2(l2 - m);
        const f32x2 rs = rcp2(e0 + e1 + e2);
        const f32x2 p0 = e0 * rs, p1 = e1 * rs, p2 = e2 * rs;

        // pass e_direct[2] from even lane to its odd partner
        f32x2 p2o;
        p2o.x = __shfl_xor(p2.x, 1);
        p2o.y = __shfl_xor(p2.y, 1);

        if (active && s < N) {
            const float4 vx = h ? make_float4(p2o.x, p0.x, p1.x, p2.x)
                                : make_float4(td.x,  tf.x, p0.x, p1.x);
            out4[(size_t)s * 58 + lane] = vx;
            if (s + 1 < N) {
                const float4 vy = h ? make_float4(p2o.y, p0.y, p1.y, p2.y)
                                    : make_float4(td.y,  tf.y, p0.y, p1.y);
                out4[(size_t)(s + 1) * 58 + lane] = vy;
            }
        }
    }
}

extern "C" void kernel_launch(void* const* d_in, const int* in_sizes, int n_in,
                              void* d_out, int out_size, void* d_ws, size_t ws_size,
                              hipStream_t stream) {
    const float* tau    = (const float*)d_in[0];
    const float* mu     = (const float*)d_in[1];
    const float* mu_bar = (const float*)d_in[2];
    const float* lw     = (const float*)d_in[3];
    const float* h2o    = (const float*)d_in[4];
    const float* o3     = (const float*)d_in[5];
    const float* co2    = (const float*)d_in[6];
    const float* uu     = (const float*)d_in[7];
    const float* n2o    = (const float*)d_in[8];
    const float* ch4    = (const float*)d_in[9];

    const float* Wd0 = (const float*)d_in[10];
    const float* bd0 = (const float*)d_in[11];
    const float* Wf0 = (const float*)d_in[12];
    const float* bf0 = (const float*)d_in[13];
    const float* Wd1 = (const float*)d_in[14];
    const float* bd1 = (const float*)d_in[15];
    const float* Wf1 = (const float*)d_in[16];
    const float* bf1 = (const float*)d_in[17];
    const float* Wd2 = (const float*)d_in[18];
    const float* bd2 = (const float*)d_in[19];
    const float* Wf2 = (const float*)d_in[20];
    const float* bf2 = (const float*)d_in[21];
    const float* Wd3 = (const float*)d_in[22];
    const float* bd3 = (const float*)d_in[23];
    const float* Wf3 = (const float*)d_in[24];
    const float* bf3 = (const float*)d_in[25];

    float* out = (float*)d_out;
    int N = in_sizes[1];  // mu has N elements

    int blocks = (N + SAMP_PER_BLK - 1) / SAMP_PER_BLK;
    lps_kernel<<<blocks, 256, 0, stream>>>(
        tau, mu, mu_bar, lw, h2o, o3, co2, uu, n2o, ch4,
        Wd0, bd0, Wf0, bf0, Wd1, bd1, Wf1, bf1,
        Wd2, bd2, Wf2, bf2, Wd3, bd3, Wf3, bf3,
        out, N);
}

// Round 6
// 82.722 us; speedup vs baseline: 8.0706x; 8.0706x over previous
//
#include <hip/hip_runtime.h>

#define EPS 1e-7f
#define NCH 29
#define SPB 128          // samples per block: 64 lanes x 2 packed (group0, group1)
#define ROWF4 59         // padded float4 stride per sample in obuf (58 + 1)

// MLP sizes: 7 -> 5 -> 4 -> 4 -> 3, per-channel weights.
// W0: [c][7][5]  b0: [c][5]
// W1: [c][5][4]  b1: [c][4]
// W2: [c][4][4]  b2: [c][4]
// W3: [c][4][3]  b3: [c][3]

typedef float f32x2 __attribute__((ext_vector_type(2)));

__device__ __forceinline__ f32x2 splat2(float v) { f32x2 r; r.x = v; r.y = v; return r; }
__device__ __forceinline__ f32x2 fma2(f32x2 a, f32x2 b, f32x2 c) {
    return __builtin_elementwise_fma(a, b, c);
}
__device__ __forceinline__ f32x2 max2(f32x2 a, f32x2 b) {
    return __builtin_elementwise_max(a, b);
}
__device__ __forceinline__ f32x2 expc2(f32x2 a) {
    f32x2 r; r.x = __expf(a.x); r.y = __expf(a.y); return r;
}
__device__ __forceinline__ f32x2 rcp2(f32x2 a) {
    f32x2 r; r.x = __builtin_amdgcn_rcpf(a.x); r.y = __builtin_amdgcn_rcpf(a.y); return r;
}

// Barrier that orders LDS traffic only (lgkmcnt), NOT global stores (vmcnt).
// __syncthreads() would emit s_waitcnt vmcnt(0) and serialize each block's
// compute against the drain of its own 59KB flush; the flushes only need
// LDS ordering. Global stores capture their VGPR sources at issue, so
// letting them remain in flight across the barrier is safe.
__device__ __forceinline__ void barrier_lds_only() {
    asm volatile("s_waitcnt lgkmcnt(0)\n\ts_barrier" ::: "memory");
}

// Packed 2-sample MLP: weights are wave-uniform scalars (SGPR), data is f32x2
// (two samples per lane) -> v_pk_fma_f32.
__device__ __forceinline__ void mlp7p(const f32x2 x[7],
    const float* __restrict__ W0, const float* __restrict__ b0,
    const float* __restrict__ W1, const float* __restrict__ b1,
    const float* __restrict__ W2, const float* __restrict__ b2,
    const float* __restrict__ W3, const float* __restrict__ b3,
    f32x2 e[3])
{
    const f32x2 zero = splat2(0.0f);
    f32x2 h0[5];
#pragma unroll
    for (int h = 0; h < 5; ++h) {
        f32x2 a = splat2(b0[h]);
#pragma unroll
        for (int f = 0; f < 7; ++f) a = fma2(x[f], splat2(W0[f * 5 + h]), a);
        h0[h] = max2(a, zero);
    }
    f32x2 h1[4];
#pragma unroll
    for (int k = 0; k < 4; ++k) {
        f32x2 a = splat2(b1[k]);
#pragma unroll
        for (int h = 0; h < 5; ++h) a = fma2(h0[h], splat2(W1[h * 4 + k]), a);
        h1[k] = max2(a, zero);
    }
    f32x2 h2[4];
#pragma unroll
    for (int k = 0; k < 4; ++k) {
        f32x2 a = splat2(b2[k]);
#pragma unroll
        for (int h = 0; h < 4; ++h) a = fma2(h1[h], splat2(W2[h * 4 + k]), a);
        h2[k] = max2(a, zero);
    }
    f32x2 l[3];
#pragma unroll
    for (int k = 0; k < 3; ++k) {
        f32x2 a = splat2(b3[k]);
#pragma unroll
        for (int h = 0; h < 4; ++h) a = fma2(h2[h], splat2(W3[h * 3 + k]), a);
        l[k] = a;
    }
    f32x2 m = max2(l[0], max2(l[1], l[2]));
    f32x2 e0 = expc2(l[0] - m);
    f32x2 e1 = expc2(l[1] - m);
    f32x2 e2 = expc2(l[2] - m);
    f32x2 rs = rcp2(e0 + e1 + e2);
    e[0] = e0 * rs; e[1] = e1 * rs; e[2] = e2 * rs;
}

__global__ __launch_bounds__(512, 4) void lps_kernel(
    const float* __restrict__ tau, const float* __restrict__ mu, const float* __restrict__ mu_bar,
    const float* __restrict__ lw, const float* __restrict__ h2o, const float* __restrict__ o3,
    const float* __restrict__ co2, const float* __restrict__ uu, const float* __restrict__ n2o,
    const float* __restrict__ ch4,
    const float* __restrict__ Wd0, const float* __restrict__ bd0,
    const float* __restrict__ Wf0, const float* __restrict__ bf0,
    const float* __restrict__ Wd1, const float* __restrict__ bd1,
    const float* __restrict__ Wf1, const float* __restrict__ bf1,
    const float* __restrict__ Wd2, const float* __restrict__ bd2,
    const float* __restrict__ Wf2, const float* __restrict__ bf2,
    const float* __restrict__ Wd3, const float* __restrict__ bd3,
    const float* __restrict__ Wf3, const float* __restrict__ bf3,
    float* __restrict__ out, int N)
{
    __shared__ __align__(16) float4 obuf[64 * ROWF4];  // 60416 B

    const int tid  = threadIdx.x;
    const int lane = tid & 63;
    const int wid  = __builtin_amdgcn_readfirstlane(tid >> 6);

    const long long base = (long long)blockIdx.x * SPB;
    const int s0 = (int)base + lane;        // group-0 sample
    const int s1 = s0 + 64;                 // group-1 sample
    const int i0 = (s0 < N) ? s0 : (N - 1);
    const int i1 = (s1 < N) ? s1 : (N - 1);

    f32x2 mu2, mub2;
    mu2.x  = mu[i0];      mu2.y  = mu[i1];
    mub2.x = mu_bar[i0];  mub2.y = mu_bar[i1];
    const f32x2 rmu2   = rcp2(mu2 + splat2(EPS));
    const f32x2 rmub2  = rcp2(mub2 + splat2(EPS));
    const f32x2 nrmu2  = -rmu2;
    const f32x2 nrmub2 = -rmub2;

    f32x2 cons2[7];
    cons2[0].x = lw[i0];  cons2[0].y = lw[i1];
    cons2[1].x = h2o[i0]; cons2[1].y = h2o[i1];
    cons2[2].x = o3[i0];  cons2[2].y = o3[i1];
    cons2[3].x = co2[i0]; cons2[3].y = co2[i1];
    cons2[4].x = uu[i0];  cons2[4].y = uu[i1];
    cons2[5].x = n2o[i0]; cons2[5].y = n2o[i1];
    cons2[6].x = ch4[i0]; cons2[6].y = ch4[i1];

    f32x2 x2d[7], x2f[7];
#pragma unroll
    for (int f = 0; f < 7; ++f) { x2d[f] = cons2[f] * rmu2; x2f[f] = cons2[f] * rmub2; }

    // Group-1 (y-half) results held in registers, statically indexed.
    float ry[4][8];

#pragma unroll
    for (int it = 0; it < 4; ++it) {
        const int c = wid + it * 8;           // wave-uniform channel
        if (c < NCH) {
            f32x2 tau2;
            tau2.x = tau[(size_t)i0 * NCH + c];
            tau2.y = tau[(size_t)i1 * NCH + c];
            f32x2 td2 = expc2(tau2 * nrmu2);
            f32x2 tf2 = expc2(tau2 * nrmub2);

            f32x2 ed[3], ef[3];
            mlp7p(x2d, Wd0 + c * 35, bd0 + c * 5, Wd1 + c * 20, bd1 + c * 4,
                       Wd2 + c * 16, bd2 + c * 4, Wd3 + c * 12, bd3 + c * 3, ed);
            mlp7p(x2f, Wf0 + c * 35, bf0 + c * 5, Wf1 + c * 20, bf1 + c * 4,
                       Wf2 + c * 16, bf2 + c * 4, Wf3 + c * 12, bf3 + c * 3, ef);

            // x-half (group 0) -> LDS now
            obuf[lane * ROWF4 + c * 2]     = make_float4(td2.x, tf2.x, ed[0].x, ed[1].x);
            obuf[lane * ROWF4 + c * 2 + 1] = make_float4(ed[2].x, ef[0].x, ef[1].x, ef[2].x);
            // y-half (group 1) -> registers
            ry[it][0] = td2.y;   ry[it][1] = tf2.y;
            ry[it][2] = ed[0].y; ry[it][3] = ed[1].y;
            ry[it][4] = ed[2].y; ry[it][5] = ef[0].y;
            ry[it][6] = ef[1].y; ry[it][7] = ef[2].y;
        }
    }

    float4* out4 = (float4*)out;

    // ---- flush group 0 (contiguous 64*928B region, full lines) ----
    barrier_lds_only();
    {
        int n0 = N - (int)base; n0 = (n0 > 64) ? 64 : n0;
        if (n0 > 0) {
            const int tot = n0 * 58;
            const long long ob = base * 58;
            for (int i = tid; i < tot; i += 512) {
                const int s = i / 58, r = i - s * 58;
                out4[ob + i] = obuf[s * ROWF4 + r];
            }
        }
    }
    barrier_lds_only();

    // ---- group-1 results regs -> LDS ----
#pragma unroll
    for (int it = 0; it < 4; ++it) {
        const int c = wid + it * 8;
        if (c < NCH) {
            obuf[lane * ROWF4 + c * 2]     = make_float4(ry[it][0], ry[it][1], ry[it][2], ry[it][3]);
            obuf[lane * ROWF4 + c * 2 + 1] = make_float4(ry[it][4], ry[it][5], ry[it][6], ry[it][7]);
        }
    }
    barrier_lds_only();

    // ---- flush group 1 ----
    {
        int n1 = N - (int)base - 64; n1 = (n1 > 64) ? 64 : n1;
        if (n1 > 0) {
            const int tot = n1 * 58;
            const long long ob = (base + 64) * 58;
            for (int i = tid; i < tot; i += 512) {
                const int s = i / 58, r = i - s * 58;
                out4[ob + i] = obuf[s * ROWF4 + r];
            }
        }
    }
}

extern "C" void kernel_launch(void* const* d_in, const int* in_sizes, int n_in,
                              void* d_out, int out_size, void* d_ws, size_t ws_size,
                              hipStream_t stream) {
    const float* tau    = (const float*)d_in[0];
    const float* mu     = (const float*)d_in[1];
    const float* mu_bar = (const float*)d_in[2];
    const float* lw     = (const float*)d_in[3];
    const float* h2o    = (const float*)d_in[4];
    const float* o3     = (const float*)d_in[5];
    const float* co2    = (const float*)d_in[6];
    const float* uu     = (const float*)d_in[7];
    const float* n2o    = (const float*)d_in[8];
    const float* ch4    = (const float*)d_in[9];

    const float* Wd0 = (const float*)d_in[10];
    const float* bd0 = (const float*)d_in[11];
    const float* Wf0 = (const float*)d_in[12];
    const float* bf0 = (const float*)d_in[13];
    const float* Wd1 = (const float*)d_in[14];
    const float* bd1 = (const float*)d_in[15];
    const float* Wf1 = (const float*)d_in[16];
    const float* bf1 = (const float*)d_in[17];
    const float* Wd2 = (const float*)d_in[18];
    const float* bd2 = (const float*)d_in[19];
    const float* Wf2 = (const float*)d_in[20];
    const float* bf2 = (const float*)d_in[21];
    const float* Wd3 = (const float*)d_in[22];
    const float* bd3 = (const float*)d_in[23];
    const float* Wf3 = (const float*)d_in[24];
    const float* bf3 = (const float*)d_in[25];

    float* out = (float*)d_out;
    int N = in_sizes[1];  // mu has N elements

    int blocks = (N + SPB - 1) / SPB;
    lps_kernel<<<blocks, 512, 0, stream>>>(
        tau, mu, mu_bar, lw, h2o, o3, co2, uu, n2o, ch4,
        Wd0, bd0, Wf0, bf0, Wd1, bd1, Wf1, bf1,
        Wd2, bd2, Wf2, bf2, Wd3, bd3, Wf3, bf3,
        out, N);
}